// Round 8
// baseline (335.594 us; speedup 1.0000x reference)
//
#include <hip/hip_runtime.h>

#define NB 128
#define NN 289   // 17*17 regions
#define ND 1024
#define NT 32
#define GAMMA1 4.0f

typedef __attribute__((ext_vector_type(4))) float f32x4;
typedef __attribute__((ext_vector_type(8))) short bf8;

// split fp32 -> hi bf16 (truncate) + lo bf16 (residual); a ~= hi + lo, err ~2^-17
__device__ inline void split2(float x, ushort &h, ushort &l) {
    uint u = __float_as_uint(x);
    h = (ushort)(u >> 16);
    float hf = __uint_as_float(u & 0xFFFF0000u);
    l = (ushort)(__float_as_uint(x - hf) >> 16);
}
// pack hi/lo bf16 into one u32: [hi16 | lo16]
__device__ inline uint packhl(float x) {
    uint u = __float_as_uint(x);
    float hf = __uint_as_float(u & 0xFFFF0000u);
    uint lo = __float_as_uint(x - hf) >> 16;
    return (u & 0xFFFF0000u) | lo;
}
// 8 packed u32 -> hi bf16x8 + lo bf16x8
__device__ inline void unpack8(const uint *u, bf8 &hi, bf8 &lo) {
    union { uint w[4]; bf8 v; } H, L;
#pragma unroll
    for (int k = 0; k < 4; ++k) {
        H.w[k] = (u[2 * k] >> 16) | (u[2 * k + 1] & 0xFFFF0000u);
        L.w[k] = (u[2 * k] & 0xFFFFu) | (u[2 * k + 1] << 16);
    }
    hi = H.v; lo = L.v;
}

// ---------------------------------------------------------------------------
// Kernel A (MFMA bf16x3): S[n,t] = sum_d ctx[n,d]*word[t,d]; softmax over t;
// E = exp(4*softmax). grid 1280 = 8 XCD * (16 batch * 10 m-tiles of 32 rows).
// block 128 = 2 waves; wave w computes rows 16w..16w+15 x all 32 t.
// ---------------------------------------------------------------------------
__global__ __launch_bounds__(128) void damsm_attn_a(
    const float* __restrict__ img, const float* __restrict__ word,
    float* __restrict__ E)
{
    // K-chunk 64, pad rows to 72 (stride 144B: 16B-aligned, bank-spread)
    __shared__ ushort sAh[32][72], sAl[32][72];
    __shared__ ushort sBh[32][72], sBl[32][72];

    const int bid = blockIdx.x;
    const int xcd = bid & 7;
    const int s   = bid >> 3;            // 0..159
    const int b   = xcd * 16 + s / 10;   // batch: 16 per XCD (word L2-resident)
    const int m   = s % 10;
    const int n0  = m * 32;

    const int tid = threadIdx.x;
    const int w   = tid >> 6;            // wave 0..1
    const int l   = tid & 63;
    const int lr  = l & 15;              // frag row/col lane part
    const int lh  = l >> 4;              // frag k-slice

    const float* __restrict__ imgb  = img  + (size_t)b * NN * ND;
    const float* __restrict__ wordb = word + (size_t)b * NT * ND;

    f32x4 acc[2];
#pragma unroll
    for (int ct = 0; ct < 2; ++ct) acc[ct] = (f32x4){0.f, 0.f, 0.f, 0.f};

    for (int kc = 0; kc < 16; ++kc) {       // 16 chunks of K=64
        // stage ctx tile 32x64 fp32 -> hi/lo planes (512 float4, 4/thread)
#pragma unroll
        for (int it = 0; it < 4; ++it) {
            int idx = tid + 128 * it;
            int row = idx >> 4;             // 0..31
            int q   = idx & 15;             // float4 col
            int n   = n0 + row;
            float4 v = make_float4(0.f, 0.f, 0.f, 0.f);
            if (n < NN)
                v = *(const float4*)(imgb + (size_t)n * ND + kc * 64 + q * 4);
            union { ushort us[4]; uint2 u2; } H, L;
            split2(v.x, H.us[0], L.us[0]); split2(v.y, H.us[1], L.us[1]);
            split2(v.z, H.us[2], L.us[2]); split2(v.w, H.us[3], L.us[3]);
            *(uint2*)(&sAh[row][q * 4]) = H.u2;
            *(uint2*)(&sAl[row][q * 4]) = L.u2;
        }
        // stage word tile 32x64
#pragma unroll
        for (int it = 0; it < 4; ++it) {
            int idx = tid + 128 * it;
            int row = idx >> 4;
            int q   = idx & 15;
            float4 v = *(const float4*)(wordb + (size_t)row * ND + kc * 64 + q * 4);
            union { ushort us[4]; uint2 u2; } H, L;
            split2(v.x, H.us[0], L.us[0]); split2(v.y, H.us[1], L.us[1]);
            split2(v.z, H.us[2], L.us[2]); split2(v.w, H.us[3], L.us[3]);
            *(uint2*)(&sBh[row][q * 4]) = H.u2;
            *(uint2*)(&sBl[row][q * 4]) = L.u2;
        }
        __syncthreads();

#pragma unroll
        for (int ks = 0; ks < 2; ++ks) {     // 2 K-steps of 32
            const int ko = ks * 32 + 8 * lh;
            bf8 ah = *(const bf8*)(&sAh[16 * w + lr][ko]);
            bf8 al = *(const bf8*)(&sAl[16 * w + lr][ko]);
#pragma unroll
            for (int ct = 0; ct < 2; ++ct) {
                bf8 bh = *(const bf8*)(&sBh[16 * ct + lr][ko]);
                bf8 bl = *(const bf8*)(&sBl[16 * ct + lr][ko]);
                acc[ct] = __builtin_amdgcn_mfma_f32_16x16x32_bf16(ah, bh, acc[ct], 0, 0, 0);
                acc[ct] = __builtin_amdgcn_mfma_f32_16x16x32_bf16(ah, bl, acc[ct], 0, 0, 0);
                acc[ct] = __builtin_amdgcn_mfma_f32_16x16x32_bf16(al, bh, acc[ct], 0, 0, 0);
            }
        }
        __syncthreads();
    }

    // softmax over t (32 vals/row: 16 lanes x 2 regs), then E = exp(4*p)
    // C/D map: row = 16w + 4*lh + r, col(t) = 16ct + lr
#pragma unroll
    for (int r = 0; r < 4; ++r) {
        float v0 = acc[0][r], v1 = acc[1][r];
        float mx = fmaxf(v0, v1);
#pragma unroll
        for (int sh = 1; sh < 16; sh <<= 1) mx = fmaxf(mx, __shfl_xor(mx, sh));
        float e0 = __expf(v0 - mx), e1 = __expf(v1 - mx);
        float ss = e0 + e1;
#pragma unroll
        for (int sh = 1; sh < 16; sh <<= 1) ss += __shfl_xor(ss, sh);
        float inv = 1.0f / ss;
        float E0 = __expf(GAMMA1 * (e0 * inv));
        float E1 = __expf(GAMMA1 * (e1 * inv));
        int n = n0 + 16 * w + 4 * lh + r;
        if (n < NN) {
            float* dst = E + ((size_t)b * NN + n) * NT;
            dst[lr]      = E0;
            dst[lr + 16] = E1;
        }
    }
}

// ---------------------------------------------------------------------------
// Kernel B (MFMA bf16x3): C'[t,d] = sum_n E[n,t]*ctx[n,d];
// out[b,d,t] = C'[t,d] / colsum[t].  grid 1024 = 128 b x 8 d-tiles of 128.
// block 256 = 4 waves; wave w: d-cols 32w..32w+31, all 32 t. K = n (10x32).
// ---------------------------------------------------------------------------
__global__ __launch_bounds__(256) void damsm_attn_b(
    const float* __restrict__ img, const float* __restrict__ E,
    float* __restrict__ out)
{
    __shared__ uint  sEt[32 * 321];   // Et packed [t][n0..320], odd stride
    __shared__ uint  sCt[128 * 33];   // ctx^T packed [d][n-chunk 32], odd stride
    __shared__ float sOut[128 * 36];  // epilogue transpose
    __shared__ float sCs[NT];

    const int bid = blockIdx.x;
    const int b   = bid >> 3;
    const int d0  = (bid & 7) * 128;

    const int tid = threadIdx.x;
    const int w   = tid >> 6;
    const int l   = tid & 63;
    const int lr  = l & 15;
    const int lh  = l >> 4;

    const float* __restrict__ Eb   = E   + (size_t)b * NN * NT;
    const float* __restrict__ imgb = img + (size_t)b * NN * ND;

    if (tid < NT) sCs[tid] = 0.f;
    __syncthreads();

    // stage Et (transposed, packed) + colsum. 2312 float4 exactly.
    for (int idx = tid; idx < (NN * NT) / 4; idx += 256) {
        int n  = idx >> 3;
        int tq = idx & 7;
        float4 v = *(const float4*)(Eb + (size_t)idx * 4);
        sEt[(tq * 4 + 0) * 321 + n] = packhl(v.x);
        sEt[(tq * 4 + 1) * 321 + n] = packhl(v.y);
        sEt[(tq * 4 + 2) * 321 + n] = packhl(v.z);
        sEt[(tq * 4 + 3) * 321 + n] = packhl(v.w);
        atomicAdd(&sCs[tq * 4 + 0], v.x);
        atomicAdd(&sCs[tq * 4 + 1], v.y);
        atomicAdd(&sCs[tq * 4 + 2], v.z);
        atomicAdd(&sCs[tq * 4 + 3], v.w);
    }
    // zero-pad n = 289..320
    for (int idx = tid; idx < 32 * 32; idx += 256) {
        int t = idx >> 5;
        int n = NN + (idx & 31);
        sEt[t * 321 + n] = 0u;
    }
    __syncthreads();
    if (tid < NT) sCs[tid] = 1.0f / sCs[tid];
    __syncthreads();

    f32x4 acc[2][2];
#pragma unroll
    for (int rt = 0; rt < 2; ++rt)
#pragma unroll
        for (int ct = 0; ct < 2; ++ct) acc[rt][ct] = (f32x4){0.f, 0.f, 0.f, 0.f};

    for (int kc = 0; kc < 10; ++kc) {        // K = n: 10 chunks of 32
        const int nc0 = kc * 32;
        // stage ctx^T chunk: read ctx[nc0..nc0+31][d0..d0+127], write packed [d][nn]
#pragma unroll
        for (int it = 0; it < 4; ++it) {
            int idx = tid + 256 * it;
            int nn  = idx >> 5;              // 0..31
            int q   = idx & 31;              // float4 col
            int n   = nc0 + nn;
            float4 v = make_float4(0.f, 0.f, 0.f, 0.f);
            if (n < NN)
                v = *(const float4*)(imgb + (size_t)n * ND + d0 + q * 4);
            sCt[(q * 4 + 0) * 33 + nn] = packhl(v.x);
            sCt[(q * 4 + 1) * 33 + nn] = packhl(v.y);
            sCt[(q * 4 + 2) * 33 + nn] = packhl(v.z);
            sCt[(q * 4 + 3) * 33 + nn] = packhl(v.w);
        }
        __syncthreads();

        // A frags (Et rows = t), both row-tiles
        uint ua[8];
        bf8 ahi[2], alo[2];
#pragma unroll
        for (int rt = 0; rt < 2; ++rt) {
            int base = (16 * rt + lr) * 321 + nc0 + 8 * lh;
#pragma unroll
            for (int e = 0; e < 8; ++e) ua[e] = sEt[base + e];
            unpack8(ua, ahi[rt], alo[rt]);
        }
#pragma unroll
        for (int ct = 0; ct < 2; ++ct) {
            int base = (32 * w + 16 * ct + lr) * 33 + 8 * lh;
            uint ub[8];
#pragma unroll
            for (int e = 0; e < 8; ++e) ub[e] = sCt[base + e];
            bf8 bhi, blo;
            unpack8(ub, bhi, blo);
#pragma unroll
            for (int rt = 0; rt < 2; ++rt) {
                acc[rt][ct] = __builtin_amdgcn_mfma_f32_16x16x32_bf16(ahi[rt], bhi, acc[rt][ct], 0, 0, 0);
                acc[rt][ct] = __builtin_amdgcn_mfma_f32_16x16x32_bf16(ahi[rt], blo, acc[rt][ct], 0, 0, 0);
                acc[rt][ct] = __builtin_amdgcn_mfma_f32_16x16x32_bf16(alo[rt], bhi, acc[rt][ct], 0, 0, 0);
            }
        }
        __syncthreads();
    }

    // epilogue: scale by 1/colsum, transpose via LDS, coalesced store
    // C/D map: t = 16rt + 4*lh + r, d = 32w + 16ct + lr
#pragma unroll
    for (int rt = 0; rt < 2; ++rt)
#pragma unroll
        for (int ct = 0; ct < 2; ++ct) {
            int dl = 32 * w + 16 * ct + lr;
#pragma unroll
            for (int r = 0; r < 4; ++r) {
                int t = 16 * rt + 4 * lh + r;
                sOut[dl * 36 + t] = acc[rt][ct][r] * sCs[t];
            }
        }
    __syncthreads();

    float* __restrict__ outb = out + (size_t)b * ND * NT;
#pragma unroll
    for (int it = 0; it < 4; ++it) {
        int idx = tid + 256 * it;
        int dl  = idx >> 3;
        int tq  = idx & 7;
        float4 v = *(const float4*)(&sOut[dl * 36 + tq * 4]);
        *(float4*)(outb + (size_t)(d0 + dl) * NT + tq * 4) = v;
    }
}

extern "C" void kernel_launch(void* const* d_in, const int* in_sizes, int n_in,
                              void* d_out, int out_size, void* d_ws, size_t ws_size,
                              hipStream_t stream) {
    const float* img  = (const float*)d_in[0];   // [128,17,17,1024] fp32
    const float* word = (const float*)d_in[1];   // [128,32,1024]   fp32
    float* out = (float*)d_out;                  // [128,1024,32]   fp32
    float* E   = (float*)d_ws;                   // [128,289,32]    fp32 (4.7 MB)

    hipLaunchKernelGGL(damsm_attn_a, dim3(1280), dim3(128), 0, stream, img, word, E);
    hipLaunchKernelGGL(damsm_attn_b, dim3(1024), dim3(256), 0, stream, img, E, out);
}

// Round 9
// 293.821 us; speedup vs baseline: 1.1422x; 1.1422x over previous
//
#include <hip/hip_runtime.h>

#define NB 128
#define NN 289   // 17*17 regions
#define ND 1024
#define NT 32
#define GAMMA1 4.0f

typedef __attribute__((ext_vector_type(4))) float f32x4;
typedef __attribute__((ext_vector_type(8))) short bf8;

// split fp32 -> hi bf16 (truncate) + lo bf16 (residual); a ~= hi + lo, err ~2^-17
__device__ inline void split2(float x, ushort &h, ushort &l) {
    uint u = __float_as_uint(x);
    h = (ushort)(u >> 16);
    float hf = __uint_as_float(u & 0xFFFF0000u);
    l = (ushort)(__float_as_uint(x - hf) >> 16);
}

// ---------------------------------------------------------------------------
// Kernel A (MFMA bf16x3): S[n,t] = sum_d ctx[n,d]*word[t,d]; softmax over t;
// E = exp(4*softmax); also accumulates colsum[b,t] = sum_n E via atomics.
// grid 1280 = 8 XCD * (16 batch * 10 m-tiles of 32 rows). block 128 = 2 waves.
// ---------------------------------------------------------------------------
__global__ __launch_bounds__(128) void damsm_attn_a(
    const float* __restrict__ img, const float* __restrict__ word,
    float* __restrict__ E, float* __restrict__ csum)
{
    __shared__ ushort sAh[32][72], sAl[32][72];
    __shared__ ushort sBh[32][72], sBl[32][72];

    const int bid = blockIdx.x;
    const int xcd = bid & 7;
    const int s   = bid >> 3;            // 0..159
    const int b   = xcd * 16 + s / 10;   // batch: 16 per XCD (word L2-resident)
    const int m   = s % 10;
    const int n0  = m * 32;

    const int tid = threadIdx.x;
    const int w   = tid >> 6;            // wave 0..1
    const int l   = tid & 63;
    const int lr  = l & 15;              // frag row/col lane part
    const int lh  = l >> 4;              // frag k-slice

    const float* __restrict__ imgb  = img  + (size_t)b * NN * ND;
    const float* __restrict__ wordb = word + (size_t)b * NT * ND;

    f32x4 acc[2];
#pragma unroll
    for (int ct = 0; ct < 2; ++ct) acc[ct] = (f32x4){0.f, 0.f, 0.f, 0.f};

    for (int kc = 0; kc < 16; ++kc) {       // 16 chunks of K=64
#pragma unroll
        for (int it = 0; it < 4; ++it) {
            int idx = tid + 128 * it;
            int row = idx >> 4;             // 0..31
            int q   = idx & 15;             // float4 col
            int n   = n0 + row;
            float4 v = make_float4(0.f, 0.f, 0.f, 0.f);
            if (n < NN)
                v = *(const float4*)(imgb + (size_t)n * ND + kc * 64 + q * 4);
            union { ushort us[4]; uint2 u2; } H, L;
            split2(v.x, H.us[0], L.us[0]); split2(v.y, H.us[1], L.us[1]);
            split2(v.z, H.us[2], L.us[2]); split2(v.w, H.us[3], L.us[3]);
            *(uint2*)(&sAh[row][q * 4]) = H.u2;
            *(uint2*)(&sAl[row][q * 4]) = L.u2;
        }
#pragma unroll
        for (int it = 0; it < 4; ++it) {
            int idx = tid + 128 * it;
            int row = idx >> 4;
            int q   = idx & 15;
            float4 v = *(const float4*)(wordb + (size_t)row * ND + kc * 64 + q * 4);
            union { ushort us[4]; uint2 u2; } H, L;
            split2(v.x, H.us[0], L.us[0]); split2(v.y, H.us[1], L.us[1]);
            split2(v.z, H.us[2], L.us[2]); split2(v.w, H.us[3], L.us[3]);
            *(uint2*)(&sBh[row][q * 4]) = H.u2;
            *(uint2*)(&sBl[row][q * 4]) = L.u2;
        }
        __syncthreads();

#pragma unroll
        for (int ks = 0; ks < 2; ++ks) {     // 2 K-steps of 32
            const int ko = ks * 32 + 8 * lh;
            bf8 ah = *(const bf8*)(&sAh[16 * w + lr][ko]);
            bf8 al = *(const bf8*)(&sAl[16 * w + lr][ko]);
#pragma unroll
            for (int ct = 0; ct < 2; ++ct) {
                bf8 bh = *(const bf8*)(&sBh[16 * ct + lr][ko]);
                bf8 bl = *(const bf8*)(&sBl[16 * ct + lr][ko]);
                acc[ct] = __builtin_amdgcn_mfma_f32_16x16x32_bf16(ah, bh, acc[ct], 0, 0, 0);
                acc[ct] = __builtin_amdgcn_mfma_f32_16x16x32_bf16(ah, bl, acc[ct], 0, 0, 0);
                acc[ct] = __builtin_amdgcn_mfma_f32_16x16x32_bf16(al, bh, acc[ct], 0, 0, 0);
            }
        }
        __syncthreads();
    }

    // softmax over t (32 vals/row), E = exp(4*p), plus colsum partials.
    // C/D map: row n = n0 + 16w + 4*lh + r, col t = 16ct + lr
    float cs0 = 0.f, cs1 = 0.f;
#pragma unroll
    for (int r = 0; r < 4; ++r) {
        float v0 = acc[0][r], v1 = acc[1][r];
        float mx = fmaxf(v0, v1);
#pragma unroll
        for (int sh = 1; sh < 16; sh <<= 1) mx = fmaxf(mx, __shfl_xor(mx, sh));
        float e0 = __expf(v0 - mx), e1 = __expf(v1 - mx);
        float ss = e0 + e1;
#pragma unroll
        for (int sh = 1; sh < 16; sh <<= 1) ss += __shfl_xor(ss, sh);
        float inv = 1.0f / ss;
        float E0 = __expf(GAMMA1 * (e0 * inv));
        float E1 = __expf(GAMMA1 * (e1 * inv));
        int n = n0 + 16 * w + 4 * lh + r;
        if (n < NN) {
            float* dst = E + ((size_t)b * NN + n) * NT;
            dst[lr]      = E0;
            dst[lr + 16] = E1;
            cs0 += E0;
            cs1 += E1;
        }
    }
    // reduce colsum over the 4 lh-groups (lanes ±16, ±32), then one atomic per t
    cs0 += __shfl_xor(cs0, 16); cs0 += __shfl_xor(cs0, 32);
    cs1 += __shfl_xor(cs1, 16); cs1 += __shfl_xor(cs1, 32);
    if (lh == 0) {
        atomicAdd(&csum[b * NT + lr], cs0);
        atomicAdd(&csum[b * NT + lr + 16], cs1);
    }
}

// ---------------------------------------------------------------------------
// Kernel B (VALU outer-product): out[b,d,t] = (1/colsum[b,t]) * sum_n ctx[n,d]*E[n,t]
// grid (8, 128): x = 128-wide d-tile, y = batch. block = 256, 3 blocks/CU.
// Thread map: p = tid/8 -> 4 d's (p*4+di); q = tid%8 -> 4 t's (q*4+tj).
// ---------------------------------------------------------------------------
__global__ __launch_bounds__(256) void damsm_attn_b(
    const float* __restrict__ img, const float* __restrict__ E,
    const float* __restrict__ csum, float* __restrict__ out)
{
    __shared__ float s_E[NN][NT];     // 37.0 KB, whole E[b]
    __shared__ float s_ctx[24][128];  // 12.3 KB n-chunk -> total 49.3 KB, 3 blk/CU

    const int b   = blockIdx.y;
    const int d0  = blockIdx.x * 128;
    const int tid = threadIdx.x;
    const int p   = tid >> 3;   // 0..31 d-group
    const int q   = tid & 7;    // 0..7 t-group

    const float* __restrict__ Eb   = E   + (size_t)b * NN * NT;
    const float* __restrict__ imgb = img + (size_t)b * NN * ND;

    // stage full E[b]: 2312 float4
    for (int idx = tid; idx < (NN * NT) / 4; idx += 256)
        ((float4*)s_E)[idx] = ((const float4*)Eb)[idx];

    // inverse colsums for this thread's 4 t's (computed by kernel A)
    float4 cs = *(const float4*)(csum + b * NT + q * 4);
    float4 ci;
    ci.x = 1.0f / cs.x; ci.y = 1.0f / cs.y; ci.z = 1.0f / cs.z; ci.w = 1.0f / cs.w;
    __syncthreads();

    float acc[4][4];
#pragma unroll
    for (int a = 0; a < 4; ++a)
#pragma unroll
        for (int c = 0; c < 4; ++c) acc[a][c] = 0.f;

    // 12 chunks of 24 n-rows (0..287), tail row 288 after
    for (int nc = 0; nc < 288; nc += 24) {
        // stage ctx chunk: 24 rows x 128 floats (768 float4, 3/thread)
#pragma unroll
        for (int it = 0; it < 3; ++it) {
            int idx = tid + 256 * it;
            int nl  = idx >> 5;        // 0..23
            int dq  = idx & 31;        // float4 col
            *(float4*)(&s_ctx[nl][dq * 4]) =
                *(const float4*)(imgb + (size_t)(nc + nl) * ND + d0 + dq * 4);
        }
        __syncthreads();
#pragma unroll 4
        for (int nn = 0; nn < 24; ++nn) {
            float4 c = *(const float4*)(&s_ctx[nn][p * 4]);
            float4 e = *(const float4*)(&s_E[nc + nn][q * 4]);
            acc[0][0] = fmaf(c.x, e.x, acc[0][0]);
            acc[0][1] = fmaf(c.x, e.y, acc[0][1]);
            acc[0][2] = fmaf(c.x, e.z, acc[0][2]);
            acc[0][3] = fmaf(c.x, e.w, acc[0][3]);
            acc[1][0] = fmaf(c.y, e.x, acc[1][0]);
            acc[1][1] = fmaf(c.y, e.y, acc[1][1]);
            acc[1][2] = fmaf(c.y, e.z, acc[1][2]);
            acc[1][3] = fmaf(c.y, e.w, acc[1][3]);
            acc[2][0] = fmaf(c.z, e.x, acc[2][0]);
            acc[2][1] = fmaf(c.z, e.y, acc[2][1]);
            acc[2][2] = fmaf(c.z, e.z, acc[2][2]);
            acc[2][3] = fmaf(c.z, e.w, acc[2][3]);
            acc[3][0] = fmaf(c.w, e.x, acc[3][0]);
            acc[3][1] = fmaf(c.w, e.y, acc[3][1]);
            acc[3][2] = fmaf(c.w, e.z, acc[3][2]);
            acc[3][3] = fmaf(c.w, e.w, acc[3][3]);
        }
        __syncthreads();
    }
    // tail row n = 288
    {
        float4 e = *(const float4*)(&s_E[288][q * 4]);
        float4 c = *(const float4*)(imgb + (size_t)288 * ND + d0 + p * 4);
        acc[0][0] = fmaf(c.x, e.x, acc[0][0]);
        acc[0][1] = fmaf(c.x, e.y, acc[0][1]);
        acc[0][2] = fmaf(c.x, e.z, acc[0][2]);
        acc[0][3] = fmaf(c.x, e.w, acc[0][3]);
        acc[1][0] = fmaf(c.y, e.x, acc[1][0]);
        acc[1][1] = fmaf(c.y, e.y, acc[1][1]);
        acc[1][2] = fmaf(c.y, e.z, acc[1][2]);
        acc[1][3] = fmaf(c.y, e.w, acc[1][3]);
        acc[2][0] = fmaf(c.z, e.x, acc[2][0]);
        acc[2][1] = fmaf(c.z, e.y, acc[2][1]);
        acc[2][2] = fmaf(c.z, e.z, acc[2][2]);
        acc[2][3] = fmaf(c.z, e.w, acc[2][3]);
        acc[3][0] = fmaf(c.w, e.x, acc[3][0]);
        acc[3][1] = fmaf(c.w, e.y, acc[3][1]);
        acc[3][2] = fmaf(c.w, e.z, acc[3][2]);
        acc[3][3] = fmaf(c.w, e.w, acc[3][3]);
    }

    // epilogue: scale by 1/colsum and store (coalesced by q)
#pragma unroll
    for (int di = 0; di < 4; ++di) {
        int d = d0 + p * 4 + di;
        float4 v;
        v.x = acc[di][0] * ci.x;
        v.y = acc[di][1] * ci.y;
        v.z = acc[di][2] * ci.z;
        v.w = acc[di][3] * ci.w;
        *(float4*)(out + (size_t)(b * ND + d) * NT + q * 4) = v;
    }
}

extern "C" void kernel_launch(void* const* d_in, const int* in_sizes, int n_in,
                              void* d_out, int out_size, void* d_ws, size_t ws_size,
                              hipStream_t stream) {
    const float* img  = (const float*)d_in[0];   // [128,17,17,1024] fp32
    const float* word = (const float*)d_in[1];   // [128,32,1024]   fp32
    float* out  = (float*)d_out;                 // [128,1024,32]   fp32
    float* csum = (float*)d_ws;                  // [128,32] colsums (16 KB)
    float* E    = csum + NB * NT;                // [128,289,32] fp32 (4.7 MB)

    // zero the colsum accumulators (ws is re-poisoned 0xAA before every call)
    hipMemsetAsync(csum, 0, NB * NT * sizeof(float), stream);

    hipLaunchKernelGGL(damsm_attn_a, dim3(1280), dim3(128), 0, stream,
                       img, word, E, csum);
    hipLaunchKernelGGL(damsm_attn_b, dim3(8, 128), dim3(256), 0, stream,
                       img, E, csum, out);
}